// Round 2
// baseline (11587.462 us; speedup 1.0000x reference)
//
#include <hip/hip_runtime.h>
#include <math.h>

#define NB 8
#define SEQ 2048
#define V 4096
#define D 1024
#define H 16
#define DH 64
#define NL 8
#define FF 4096
#define TVAL 2049
#define MVAL (NB*TVAL)
#define MPAD 16512
#define TS 2112

typedef unsigned short u16;
typedef __attribute__((ext_vector_type(8))) __bf16 bfrag;
typedef __attribute__((ext_vector_type(4))) float f32x4;
typedef __attribute__((ext_vector_type(8))) unsigned short us8;
typedef __attribute__((ext_vector_type(4))) float fvec4;

__device__ __forceinline__ float b2f(u16 u) {
  union { unsigned int i; float f; } x; x.i = ((unsigned int)u) << 16; return x.f;
}
__device__ __forceinline__ u16 f2b(float f) {
  union { float f; unsigned int i; } x; x.f = f;
  unsigned int r = x.i + 0x7FFFu + ((x.i >> 16) & 1u);
  return (u16)(r >> 16);
}
__device__ __forceinline__ float phi_fn(float x) { return x > 0.f ? x + 1.f : __expf(x); }

__device__ __forceinline__ void async16(const u16* g, u16* l) {
  auto gp = (const __attribute__((address_space(1))) unsigned int*)(unsigned long long)g;
  auto lp = (__attribute__((address_space(3))) unsigned int*)(unsigned int)(unsigned long long)l;
  __builtin_amdgcn_global_load_lds(gp, lp, 16, 0, 0);
}

__device__ __forceinline__ f32x4 mfma16(bfrag a, bfrag b, f32x4 c) {
  return __builtin_amdgcn_mfma_f32_16x16x32_bf16(a, b, c, 0, 0, 0);
}

// ---------------- helper kernels ----------------

__global__ __launch_bounds__(256) void conv_kernel(const float* __restrict__ src,
                                                   u16* __restrict__ dst, long n) {
  long i = ((long)blockIdx.x * 256 + threadIdx.x) * 4;
  if (i < n) {
    fvec4 v = *(const fvec4*)(src + i);
    u16 o[4];
    #pragma unroll
    for (int j = 0; j < 4; ++j) o[j] = f2b(v[j]);
    *(uint2*)(dst + i) = *(const uint2*)o;
  }
}

__global__ __launch_bounds__(256) void transposeW(const float* __restrict__ src,
                                                  u16* __restrict__ dst, int K, int N) {
  const int z = blockIdx.z;
  src += (size_t)z * K * N;
  dst += (size_t)z * K * N;
  const int k0 = blockIdx.x * 64, n0 = blockIdx.y * 64;
  __shared__ __align__(16) u16 t[64][65];
  const int c = threadIdx.x & 63, r4 = threadIdx.x >> 6;
  #pragma unroll 4
  for (int i = 0; i < 16; ++i) {
    int k = i * 4 + r4;
    t[c][k] = f2b(src[(size_t)(k0 + k) * N + n0 + c]);
  }
  __syncthreads();
  #pragma unroll 4
  for (int i = 0; i < 16; ++i) {
    int nr = i * 4 + r4;
    dst[(size_t)(n0 + nr) * K + k0 + c] = t[nr][c];
  }
}

__global__ __launch_bounds__(256) void rope_table(float* __restrict__ ct, float* __restrict__ snt) {
  int idx = blockIdx.x * 256 + threadIdx.x;
  if (idx < TVAL * 32) {
    int s = idx >> 5, p = idx & 31;
    float ang = (float)s * powf(10000.f, -(float)p / 32.f);
    ct[idx] = cosf(ang);
    snt[idx] = sinf(ang);
  }
}

__global__ __launch_bounds__(256) void cls_kernel(const float* __restrict__ We,
                                                  const float* __restrict__ be,
                                                  const float* __restrict__ pos,
                                                  u16* __restrict__ xb, float* __restrict__ xf) {
  int n = blockIdx.x;
  for (int c = threadIdx.x; c < D; c += 256) {
    float v = We[(size_t)(V - 1) * D + c] + be[c] + pos[c];
    size_t idx = (size_t)(n * TVAL) * D + c;
    xb[idx] = f2b(v);
    xf[idx] = v;
  }
}

// ---------------- main GEMM ----------------
// C[M,N] = A[M,K] @ Bt[N,K]^T ; EPI: 0=embed(remap+pos, bf16+f32 out)
// 1=bias->bf16 ; 2=bias+res(f32)->f32 ; 3=bias+gelu->bf16
template<int EPI>
__global__ __launch_bounds__(256) void gemm_bt(
    const u16* __restrict__ A, const u16* __restrict__ Bt,
    const float* __restrict__ bias, const float* __restrict__ resf,
    const float* __restrict__ pos, u16* __restrict__ Cb, float* __restrict__ Cf,
    int N, int K) {
  __shared__ __align__(16) u16 sA[4096];
  __shared__ __align__(16) u16 sB[4096];
  const int tid = threadIdx.x, wave = tid >> 6, lane = tid & 63;
  const int fr = lane & 15, fc8 = (lane >> 4) << 3;
  const int rA = blockIdx.y * 128, rB = blockIdx.x * 128;
  const u16* gA0 = A + (size_t)(rA + wave * 16 + fr) * K + fc8;
  const u16* gA1 = A + (size_t)(rA + 64 + wave * 16 + fr) * K + fc8;
  const u16* gB0 = Bt + (size_t)(rB + wave * 16 + fr) * K + fc8;
  const u16* gB1 = Bt + (size_t)(rB + 64 + wave * 16 + fr) * K + fc8;
  u16* lA0 = sA + wave * 512;
  u16* lA1 = sA + (4 + wave) * 512;
  u16* lB0 = sB + wave * 512;
  u16* lB1 = sB + (4 + wave) * 512;
  const int wm = wave & 1, wn = wave >> 1;
  f32x4 acc[4][4];
  #pragma unroll
  for (int mt = 0; mt < 4; ++mt)
    #pragma unroll
    for (int nt = 0; nt < 4; ++nt)
      #pragma unroll
      for (int r = 0; r < 4; ++r) acc[mt][nt][r] = 0.f;

  for (int kk = 0; kk < K; kk += 32) {
    __syncthreads();
    async16(gA0 + kk, lA0);
    async16(gA1 + kk, lA1);
    async16(gB0 + kk, lB0);
    async16(gB1 + kk, lB1);
    __syncthreads();
    bfrag af[4], bfr[4];
    #pragma unroll
    for (int t = 0; t < 4; ++t) af[t] = *(const bfrag*)(sA + (wm * 4 + t) * 512 + lane * 8);
    #pragma unroll
    for (int t = 0; t < 4; ++t) bfr[t] = *(const bfrag*)(sB + (wn * 4 + t) * 512 + lane * 8);
    #pragma unroll
    for (int mt = 0; mt < 4; ++mt)
      #pragma unroll
      for (int nt = 0; nt < 4; ++nt)
        acc[mt][nt] = mfma16(af[mt], bfr[nt], acc[mt][nt]);
  }

  const int r0 = rA + wm * 64;
  const int c0 = rB + wn * 64;
  #pragma unroll
  for (int mt = 0; mt < 4; ++mt) {
    #pragma unroll
    for (int nt = 0; nt < 4; ++nt) {
      int col = c0 + nt * 16 + fr;
      float bi = bias[col];
      f32x4 v = acc[mt][nt];
      #pragma unroll
      for (int r = 0; r < 4; ++r) {
        int row = r0 + mt * 16 + ((lane >> 4) << 2) + r;
        float val = v[r] + bi;
        if (EPI == 0) {
          int bidx = row >> 11;
          int s = row & 2047;
          size_t orow = (size_t)bidx * TVAL + s + 1;
          float tt = val + pos[(size_t)(s + 1) * D + col];
          Cb[orow * D + col] = f2b(tt);
          Cf[orow * D + col] = tt;
        } else if (EPI == 1) {
          Cb[(size_t)row * N + col] = f2b(val);
        } else if (EPI == 2) {
          Cf[(size_t)row * N + col] = val + resf[(size_t)row * N + col];
        } else {
          float gl = 0.5f * val * (1.f + erff(val * 0.70710678118f));
          Cb[(size_t)row * N + col] = f2b(gl);
        }
      }
    }
  }
}

// ---------------- rope + phi + K/V transpose ----------------
__global__ __launch_bounds__(256) void rope_kernel(
    u16* qb, const u16* __restrict__ kb, const u16* __restrict__ vb,
    u16* __restrict__ Kt, u16* __restrict__ Vt,
    const float* __restrict__ ct, const float* __restrict__ snt) {
  const int stile = blockIdx.x, h = blockIdx.y, n = blockIdx.z;
  const int tid = threadIdx.x;
  const int sl = tid >> 2;
  const int g8 = (tid & 3) << 3;
  const int s = stile * 64 + sl;
  const bool valid = s < TVAL;
  const size_t row = (size_t)n * TVAL + s;
  float ql[8], qh[8], kl[8], kh[8];
  us8 vlo = {0,0,0,0,0,0,0,0}, vhi = {0,0,0,0,0,0,0,0};
  if (valid) {
    const u16* qp = qb + row * D + (size_t)h * DH;
    const u16* kp = kb + row * D + (size_t)h * DH;
    const u16* vp = vb + row * D + (size_t)h * DH;
    us8 a = *(const us8*)(qp + g8);
    us8 b = *(const us8*)(qp + 32 + g8);
    us8 c = *(const us8*)(kp + g8);
    us8 d = *(const us8*)(kp + 32 + g8);
    vlo = *(const us8*)(vp + g8);
    vhi = *(const us8*)(vp + 32 + g8);
    #pragma unroll
    for (int j = 0; j < 8; ++j) {
      ql[j] = b2f(a[j]); qh[j] = b2f(b[j]);
      kl[j] = b2f(c[j]); kh[j] = b2f(d[j]);
    }
  } else {
    #pragma unroll
    for (int j = 0; j < 8; ++j) { ql[j] = qh[j] = kl[j] = kh[j] = 0.f; }
  }
  const int se = valid ? s : 0;
  us8 qolo, qohi;
  u16 kolo[8], kohi[8];
  #pragma unroll
  for (int j = 0; j < 8; ++j) {
    float c = ct[se * 32 + g8 + j];
    float sn = snt[se * 32 + g8 + j];
    float x1 = ql[j] * c - qh[j] * sn;
    float x2 = qh[j] * c + ql[j] * sn;
    qolo[j] = f2b(phi_fn(x1));
    qohi[j] = f2b(phi_fn(x2));
    float y1 = kl[j] * c - kh[j] * sn;
    float y2 = kh[j] * c + kl[j] * sn;
    kolo[j] = f2b(phi_fn(y1));
    kohi[j] = f2b(phi_fn(y2));
  }
  if (valid) {
    u16* qp = qb + row * D + (size_t)h * DH;
    *(us8*)(qp + g8) = qolo;
    *(us8*)(qp + 32 + g8) = qohi;
  }
  __shared__ __align__(16) u16 tile[64][72];
  #pragma unroll
  for (int j = 0; j < 8; ++j) {
    tile[g8 + j][sl] = valid ? kolo[j] : (u16)0;
    tile[32 + g8 + j][sl] = valid ? kohi[j] : (u16)0;
  }
  __syncthreads();
  {
    const int dr = tid >> 2, ck = (tid & 3) << 4;
    const size_t ob = ((size_t)(n * H + h) * DH + dr) * TS + (size_t)stile * 64 + ck;
    us8 t0 = *(const us8*)&tile[dr][ck];
    us8 t1 = *(const us8*)&tile[dr][ck + 8];
    *(us8*)(Kt + ob) = t0;
    *(us8*)(Kt + ob + 8) = t1;
  }
  __syncthreads();
  #pragma unroll
  for (int j = 0; j < 8; ++j) {
    tile[g8 + j][sl] = valid ? vlo[j] : (u16)0;
    tile[32 + g8 + j][sl] = valid ? vhi[j] : (u16)0;
  }
  __syncthreads();
  {
    const int dr = tid >> 2, ck = (tid & 3) << 4;
    const size_t ob = ((size_t)(n * H + h) * DH + dr) * TS + (size_t)stile * 64 + ck;
    us8 t0 = *(const us8*)&tile[dr][ck];
    us8 t1 = *(const us8*)&tile[dr][ck + 8];
    *(us8*)(Vt + ob) = t0;
    *(us8*)(Vt + ob + 8) = t1;
  }
}

// ---------------- KV^T + Ksum per (n,h) ----------------
__global__ __launch_bounds__(256) void kv_kernel(
    const u16* __restrict__ Kt, const u16* __restrict__ Vt,
    u16* __restrict__ KVt, float* __restrict__ Ksum) {
  const int nh = blockIdx.x;
  const int tid = threadIdx.x, wave = tid >> 6, lane = tid & 63;
  const size_t base = (size_t)nh * DH * TS;
  const int fr = lane & 15, fc = (lane >> 4) << 3;
  f32x4 acc[4][4];
  #pragma unroll
  for (int a = 0; a < 4; ++a)
    #pragma unroll
    for (int b = 0; b < 4; ++b)
      #pragma unroll
      for (int r = 0; r < 4; ++r) acc[a][b][r] = 0.f;
  for (int c = wave; c < TS / 32; c += 4) {
    const int s0 = c * 32 + fc;
    bfrag av[4], bk[4];
    #pragma unroll
    for (int t = 0; t < 4; ++t) {
      av[t] = *(const bfrag*)(Vt + base + (size_t)(t * 16 + fr) * TS + s0);
      bk[t] = *(const bfrag*)(Kt + base + (size_t)(t * 16 + fr) * TS + s0);
    }
    #pragma unroll
    for (int mt = 0; mt < 4; ++mt)
      #pragma unroll
      for (int dt = 0; dt < 4; ++dt)
        acc[mt][dt] = mfma16(av[mt], bk[dt], acc[mt][dt]);
  }
  __shared__ float red[4096];
  for (int i = tid; i < 4096; i += 256) red[i] = 0.f;
  __syncthreads();
  #pragma unroll
  for (int mt = 0; mt < 4; ++mt)
    #pragma unroll
    for (int dt = 0; dt < 4; ++dt)
      #pragma unroll
      for (int r = 0; r < 4; ++r) {
        int m = mt * 16 + ((lane >> 4) << 2) + r;
        int dd = dt * 16 + fr;
        atomicAdd(&red[m * 64 + dd], acc[mt][dt][r]);
      }
  __syncthreads();
  for (int i = tid; i < 4096; i += 256) KVt[(size_t)nh * 4096 + i] = f2b(red[i]);
  // Ksum over s of Kt rows
  float ks = 0.f;
  const int dd = tid & 63, part = tid >> 6;
  for (int s = part * (TS / 4); s < (part + 1) * (TS / 4); s += 8) {
    us8 t = *(const us8*)(Kt + base + (size_t)dd * TS + s);
    #pragma unroll
    for (int j = 0; j < 8; ++j) ks += b2f(t[j]);
  }
  __shared__ float ksr[64];
  if (tid < 64) ksr[tid] = 0.f;
  __syncthreads();
  atomicAdd(&ksr[dd], ks);
  __syncthreads();
  if (tid < 64) Ksum[nh * 64 + tid] = ksr[tid];
}

// ---------------- Z = 1/(Qf . Ksum + eps) ----------------
__global__ __launch_bounds__(256) void z_kernel(const u16* __restrict__ qb,
                                                const float* __restrict__ Ksum,
                                                float* __restrict__ Z) {
  const int tid = threadIdx.x;
  const int row = blockIdx.x * 16 + (tid >> 4);
  const int h = tid & 15;
  if (row >= MVAL) return;
  const int n = row / TVAL;
  const u16* qp = qb + (size_t)row * D + h * DH;
  const float* kp = Ksum + (size_t)(n * 16 + h) * 64;
  float acc = 0.f;
  #pragma unroll
  for (int j = 0; j < 64; j += 8) {
    us8 t = *(const us8*)(qp + j);
    #pragma unroll
    for (int j2 = 0; j2 < 8; ++j2) acc += b2f(t[j2]) * kp[j + j2];
  }
  Z[(size_t)row * 16 + h] = 1.f / (acc + 1e-6f);
}

// ---------------- attn = (Qf @ KVt^T) * Z ----------------
__global__ __launch_bounds__(256) void attn_kernel(
    const u16* __restrict__ qb, const u16* __restrict__ KVt,
    const float* __restrict__ Z, u16* __restrict__ attnb) {
  const int mt5 = blockIdx.x, nh = blockIdx.y, n = nh >> 4, h = nh & 15;
  const int tid = threadIdx.x, wave = tid >> 6, lane = tid & 63;
  const int fr = lane & 15, fc = (lane >> 4) << 3;
  f32x4 acc[2][4];
  #pragma unroll
  for (int a = 0; a < 2; ++a)
    #pragma unroll
    for (int b = 0; b < 4; ++b)
      #pragma unroll
      for (int r = 0; r < 4; ++r) acc[a][b][r] = 0.f;
  #pragma unroll
  for (int kc = 0; kc < 2; ++kc) {
    bfrag aq[2], bkv[4];
    #pragma unroll
    for (int m2 = 0; m2 < 2; ++m2) {
      int sr = mt5 * 128 + wave * 32 + m2 * 16 + fr;
      if (sr > 2048) sr = 2048;
      aq[m2] = *(const bfrag*)(qb + ((size_t)n * TVAL + sr) * D + h * DH + kc * 32 + fc);
    }
    #pragma unroll
    for (int nt = 0; nt < 4; ++nt)
      bkv[nt] = *(const bfrag*)(KVt + (size_t)nh * 4096 + (nt * 16 + fr) * 64 + kc * 32 + fc);
    #pragma unroll
    for (int m2 = 0; m2 < 2; ++m2)
      #pragma unroll
      for (int nt = 0; nt < 4; ++nt)
        acc[m2][nt] = mfma16(aq[m2], bkv[nt], acc[m2][nt]);
  }
  #pragma unroll
  for (int m2 = 0; m2 < 2; ++m2)
    #pragma unroll
    for (int nt = 0; nt < 4; ++nt)
      #pragma unroll
      for (int r = 0; r < 4; ++r) {
        int s = mt5 * 128 + wave * 32 + m2 * 16 + ((lane >> 4) << 2) + r;
        if (s < TVAL) {
          size_t row = (size_t)n * TVAL + s;
          float z = Z[row * 16 + h];
          attnb[row * D + h * DH + nt * 16 + fr] = f2b(acc[m2][nt][r] * z);
        }
      }
}

// ---------------- LayerNorm (f32 in -> bf16 out [, f32 out]) ----------------
template<bool WF>
__global__ __launch_bounds__(256) void ln_kernel(const float* in, const float* __restrict__ g,
                                                 const float* __restrict__ b,
                                                 u16* __restrict__ ob, float* of) {
  const int tid = threadIdx.x, wave = tid >> 6, lane = tid & 63;
  const size_t row = (size_t)blockIdx.x * 4 + wave;
  const float* rp = in + row * D + lane * 16;
  float v[16];
  #pragma unroll
  for (int i = 0; i < 16; i += 4) {
    fvec4 t = *(const fvec4*)(rp + i);
    v[i] = t[0]; v[i + 1] = t[1]; v[i + 2] = t[2]; v[i + 3] = t[3];
  }
  float s = 0.f, s2 = 0.f;
  #pragma unroll
  for (int i = 0; i < 16; ++i) { s += v[i]; s2 += v[i] * v[i]; }
  #pragma unroll
  for (int m = 1; m < 64; m <<= 1) { s += __shfl_xor(s, m); s2 += __shfl_xor(s2, m); }
  float mean = s * (1.f / 1024.f);
  float var = s2 * (1.f / 1024.f) - mean * mean;
  float rstd = rsqrtf(var + 1e-5f);
  const int c0 = lane * 16;
  us8 o0, o1;
  #pragma unroll
  for (int i = 0; i < 16; ++i) {
    float o = (v[i] - mean) * rstd * g[c0 + i] + b[c0 + i];
    if (i < 8) o0[i] = f2b(o); else o1[i - 8] = f2b(o);
    if (WF) of[row * D + c0 + i] = o;
  }
  *(us8*)(ob + row * D + c0) = o0;
  *(us8*)(ob + row * D + c0 + 8) = o1;
}

// ---------------- final LN on CLS rows ----------------
__global__ __launch_bounds__(256) void lnf_kernel(const float* __restrict__ xf,
                                                  const float* __restrict__ gN,
                                                  const float* __restrict__ bN,
                                                  float* __restrict__ lnf) {
  const int n = blockIdx.x, tid = threadIdx.x;
  const float* rp = xf + (size_t)n * TVAL * D;
  float v[4];
  #pragma unroll
  for (int i = 0; i < 4; ++i) v[i] = rp[tid * 4 + i];
  float s = v[0] + v[1] + v[2] + v[3];
  float s2 = v[0]*v[0] + v[1]*v[1] + v[2]*v[2] + v[3]*v[3];
  #pragma unroll
  for (int m = 1; m < 64; m <<= 1) { s += __shfl_xor(s, m); s2 += __shfl_xor(s2, m); }
  __shared__ float rs[4], rs2[4];
  const int wave = tid >> 6, lane = tid & 63;
  if (lane == 0) { rs[wave] = s; rs2[wave] = s2; }
  __syncthreads();
  s = rs[0] + rs[1] + rs[2] + rs[3];
  s2 = rs2[0] + rs2[1] + rs2[2] + rs2[3];
  float mean = s * (1.f / 1024.f);
  float var = s2 * (1.f / 1024.f) - mean * mean;
  float rstd = rsqrtf(var + 1e-5f);
  #pragma unroll
  for (int i = 0; i < 4; ++i) {
    int c = tid * 4 + i;
    lnf[n * D + c] = (v[i] - mean) * rstd * gN[c] + bN[c];
  }
}

// ---------------- out = lnf @ Wout + bout ----------------
__global__ __launch_bounds__(256) void out_kernel(const float* __restrict__ lnf,
                                                  const float* __restrict__ Wout,
                                                  const float* __restrict__ bout,
                                                  float* __restrict__ out) {
  __shared__ float xs[8 * 1024];
  for (int i = threadIdx.x; i < 8192; i += 256) xs[i] = lnf[i];
  __syncthreads();
  const int j = blockIdx.x * 256 + threadIdx.x;
  float acc[8];
  float bj = bout[j];
  #pragma unroll
  for (int n = 0; n < 8; ++n) acc[n] = bj;
  for (int k = 0; k < 1024; ++k) {
    float w = Wout[(size_t)k * 4096 + j];
    #pragma unroll
    for (int n = 0; n < 8; ++n) acc[n] += xs[n * 1024 + k] * w;
  }
  #pragma unroll
  for (int n = 0; n < 8; ++n) out[(size_t)n * 4096 + j] = acc[n];
}

// ---------------- host ----------------
extern "C" void kernel_launch(void* const* d_in, const int* in_sizes, int n_in,
                              void* d_out, int out_size, void* d_ws, size_t ws_size,
                              hipStream_t stream) {
  const float* inputs = (const float*)d_in[0];
  const float* We   = (const float*)d_in[1];
  const float* be   = (const float*)d_in[2];
  const float* pos  = (const float*)d_in[3];
  const float* Wq   = (const float*)d_in[4];
  const float* bq   = (const float*)d_in[5];
  const float* Wk   = (const float*)d_in[6];
  const float* bk   = (const float*)d_in[7];
  const float* Wv   = (const float*)d_in[8];
  const float* bv   = (const float*)d_in[9];
  const float* Wo   = (const float*)d_in[10];
  const float* bo   = (const float*)d_in[11];
  const float* ln1g = (const float*)d_in[12];
  const float* ln1b = (const float*)d_in[13];
  const float* W1   = (const float*)d_in[14];
  const float* b1   = (const float*)d_in[15];
  const float* W2   = (const float*)d_in[16];
  const float* b2   = (const float*)d_in[17];
  const float* ln2g = (const float*)d_in[18];
  const float* ln2b = (const float*)d_in[19];
  const float* gN   = (const float*)d_in[20];
  const float* bN   = (const float*)d_in[21];
  const float* Wout = (const float*)d_in[22];
  const float* bout = (const float*)d_in[23];
  float* out = (float*)d_out;

  char* p = (char*)d_ws;
  auto alloc = [&](size_t b) { char* r = p; p += (b + 255) & ~(size_t)255; return r; };
  u16*   xb   = (u16*)alloc((size_t)MPAD * D * 2);
  float* xf   = (float*)alloc((size_t)MPAD * D * 4);
  float* hf   = (float*)alloc((size_t)MPAD * D * 4);
  u16*   qb   = (u16*)alloc((size_t)MPAD * D * 2);
  u16*   kb   = (u16*)alloc((size_t)MPAD * D * 2);
  u16*   vb   = (u16*)alloc((size_t)MPAD * D * 2);
  u16*   Kt   = (u16*)alloc((size_t)128 * DH * TS * 2);
  u16*   Vt   = (u16*)alloc((size_t)128 * DH * TS * 2);
  u16*   ffb  = (u16*)alloc((size_t)MPAD * FF * 2);
  u16*   inb  = ffb;  // alias: inputs_bf16 used only before ffn
  u16*   WeT  = (u16*)alloc((size_t)V * D * 2);
  u16*   WqT  = (u16*)alloc((size_t)D * D * 2);
  u16*   WkT  = (u16*)alloc((size_t)D * D * 2);
  u16*   WvT  = (u16*)alloc((size_t)D * D * 2);
  u16*   WoT  = (u16*)alloc((size_t)D * D * 2);
  u16*   W1T  = (u16*)alloc((size_t)D * FF * 2);
  u16*   W2T  = (u16*)alloc((size_t)FF * D * 2);
  u16*   KVt  = (u16*)alloc((size_t)128 * 64 * 64 * 2);
  float* Ksum = (float*)alloc((size_t)128 * 64 * 4);
  float* Zb   = (float*)alloc((size_t)MPAD * 16 * 4);
  float* ct   = (float*)alloc((size_t)TVAL * 32 * 4);
  float* snt  = (float*)alloc((size_t)TVAL * 32 * 4);
  float* lnf  = (float*)alloc((size_t)8 * D * 4);

  hipMemsetAsync(Kt, 0, (size_t)128 * DH * TS * 2, stream);
  hipMemsetAsync(Vt, 0, (size_t)128 * DH * TS * 2, stream);
  rope_table<<<(TVAL * 32 + 255) / 256, 256, 0, stream>>>(ct, snt);
  conv_kernel<<<65536, 256, 0, stream>>>(inputs, inb, (long)NB * SEQ * V);
  transposeW<<<dim3(V / 64, D / 64, 1), 256, 0, stream>>>(We, WeT, V, D);
  cls_kernel<<<8, 256, 0, stream>>>(We, be, pos, xb, xf);
  gemm_bt<0><<<dim3(D / 128, 16384 / 128), 256, 0, stream>>>(
      inb, WeT, be, nullptr, pos, xb, xf, D, V);

  for (int l = 0; l < NL; ++l) {
    transposeW<<<dim3(16, 16, 1), 256, 0, stream>>>(Wq + (size_t)l * D * D, WqT, D, D);
    transposeW<<<dim3(16, 16, 1), 256, 0, stream>>>(Wk + (size_t)l * D * D, WkT, D, D);
    transposeW<<<dim3(16, 16, 1), 256, 0, stream>>>(Wv + (size_t)l * D * D, WvT, D, D);
    transposeW<<<dim3(16, 16, 1), 256, 0, stream>>>(Wo + (size_t)l * D * D, WoT, D, D);
    transposeW<<<dim3(16, 64, 1), 256, 0, stream>>>(W1 + (size_t)l * D * FF, W1T, D, FF);
    transposeW<<<dim3(64, 16, 1), 256, 0, stream>>>(W2 + (size_t)l * FF * D, W2T, FF, D);

    gemm_bt<1><<<dim3(8, 129), 256, 0, stream>>>(xb, WqT, bq + l * D, nullptr, nullptr, qb, nullptr, D, D);
    gemm_bt<1><<<dim3(8, 129), 256, 0, stream>>>(xb, WkT, bk + l * D, nullptr, nullptr, kb, nullptr, D, D);
    gemm_bt<1><<<dim3(8, 129), 256, 0, stream>>>(xb, WvT, bv + l * D, nullptr, nullptr, vb, nullptr, D, D);
    rope_kernel<<<dim3(33, 16, 8), 256, 0, stream>>>(qb, kb, vb, Kt, Vt, ct, snt);
    kv_kernel<<<128, 256, 0, stream>>>(Kt, Vt, KVt, Ksum);
    z_kernel<<<(MVAL + 15) / 16, 256, 0, stream>>>(qb, Ksum, Zb);
    attn_kernel<<<dim3(17, 128), 256, 0, stream>>>(qb, KVt, Zb, vb);
    // hf = x + attn@Wo + bo   (pre-LN1)
    gemm_bt<2><<<dim3(8, 129), 256, 0, stream>>>(vb, WoT, bo + l * D, xf, nullptr, nullptr, hf, D, D);
    // x1 = LN1(hf): qb = bf16(x1) for FF GEMM, xf = fp32 x1 (FF residual base)
    ln_kernel<true><<<MPAD / 4, 256, 0, stream>>>(hf, ln1g + l * D, ln1b + l * D, qb, xf);
    gemm_bt<3><<<dim3(32, 129), 256, 0, stream>>>(qb, W1T, b1 + l * FF, nullptr, nullptr, ffb, nullptr, FF, D);
    // hf = x1 + ff@W2 + b2   (pre-LN2)
    gemm_bt<2><<<dim3(8, 129), 256, 0, stream>>>(ffb, W2T, b2 + l * D, xf, nullptr, nullptr, hf, D, FF);
    // x2 = LN2(hf): xb = bf16(x2), xf = fp32 x2 (next layer input + residual)
    ln_kernel<true><<<MPAD / 4, 256, 0, stream>>>(hf, ln2g + l * D, ln2b + l * D, xb, xf);
  }

  lnf_kernel<<<8, 256, 0, stream>>>(xf, gN, bN, lnf);
  out_kernel<<<16, 256, 0, stream>>>(lnf, Wout, bout, out);
}

// Round 3
// 10871.044 us; speedup vs baseline: 1.0659x; 1.0659x over previous
//
#include <hip/hip_runtime.h>
#include <math.h>

#define NB 8
#define SEQ 2048
#define V 4096
#define D 1024
#define H 16
#define DH 64
#define NL 8
#define FF 4096
#define TVAL 2049
#define MVAL (NB*TVAL)
#define MPAD 16512
#define TS 2112
#define QS 3072   // fused qkv row stride

typedef unsigned short u16;
typedef __attribute__((ext_vector_type(8))) __bf16 bfrag;
typedef __attribute__((ext_vector_type(4))) float f32x4;
typedef __attribute__((ext_vector_type(8))) unsigned short us8;
typedef __attribute__((ext_vector_type(4))) float fvec4;

__device__ __forceinline__ float b2f(u16 u) {
  union { unsigned int i; float f; } x; x.i = ((unsigned int)u) << 16; return x.f;
}
__device__ __forceinline__ u16 f2b(float f) {
  union { float f; unsigned int i; } x; x.f = f;
  unsigned int r = x.i + 0x7FFFu + ((x.i >> 16) & 1u);
  return (u16)(r >> 16);
}
__device__ __forceinline__ float phi_fn(float x) { return x > 0.f ? x + 1.f : __expf(x); }

__device__ __forceinline__ void async16(const u16* g, u16* l) {
  auto gp = (const __attribute__((address_space(1))) unsigned int*)(unsigned long long)g;
  auto lp = (__attribute__((address_space(3))) unsigned int*)(unsigned int)(unsigned long long)l;
  __builtin_amdgcn_global_load_lds(gp, lp, 16, 0, 0);
}

__device__ __forceinline__ f32x4 mfma16(bfrag a, bfrag b, f32x4 c) {
  return __builtin_amdgcn_mfma_f32_16x16x32_bf16(a, b, c, 0, 0, 0);
}

// ---------------- helper kernels ----------------

__global__ __launch_bounds__(256) void conv_kernel(const float* __restrict__ src,
                                                   u16* __restrict__ dst, long n) {
  long i = ((long)blockIdx.x * 256 + threadIdx.x) * 4;
  if (i < n) {
    fvec4 v = *(const fvec4*)(src + i);
    u16 o[4];
    #pragma unroll
    for (int j = 0; j < 4; ++j) o[j] = f2b(v[j]);
    *(uint2*)(dst + i) = *(const uint2*)o;
  }
}

__global__ __launch_bounds__(256) void transposeW(const float* __restrict__ src,
                                                  u16* __restrict__ dst, int K, int N) {
  const int z = blockIdx.z;
  src += (size_t)z * K * N;
  dst += (size_t)z * K * N;
  const int k0 = blockIdx.x * 64, n0 = blockIdx.y * 64;
  __shared__ __align__(16) u16 t[64][65];
  const int c = threadIdx.x & 63, r4 = threadIdx.x >> 6;
  #pragma unroll 4
  for (int i = 0; i < 16; ++i) {
    int k = i * 4 + r4;
    t[c][k] = f2b(src[(size_t)(k0 + k) * N + n0 + c]);
  }
  __syncthreads();
  #pragma unroll 4
  for (int i = 0; i < 16; ++i) {
    int nr = i * 4 + r4;
    dst[(size_t)(n0 + nr) * K + k0 + c] = t[nr][c];
  }
}

__global__ __launch_bounds__(256) void rope_table(float* __restrict__ ct, float* __restrict__ snt) {
  int idx = blockIdx.x * 256 + threadIdx.x;
  if (idx < TVAL * 32) {
    int s = idx >> 5, p = idx & 31;
    float ang = (float)s * powf(10000.f, -(float)p / 32.f);
    ct[idx] = cosf(ang);
    snt[idx] = sinf(ang);
  }
}

__global__ __launch_bounds__(256) void pack_bias(const float* __restrict__ bq,
                                                 const float* __restrict__ bk,
                                                 const float* __restrict__ bv,
                                                 float* __restrict__ bqkv) {
  int i = blockIdx.x * 256 + threadIdx.x;
  if (i >= NL * QS) return;
  int l = i / QS, j = i - l * QS;
  float v = (j < 1024) ? bq[l * 1024 + j]
          : (j < 2048) ? bk[l * 1024 + j - 1024]
                       : bv[l * 1024 + j - 2048];
  bqkv[i] = v;
}

__global__ __launch_bounds__(256) void cls_kernel(const float* __restrict__ We,
                                                  const float* __restrict__ be,
                                                  const float* __restrict__ pos,
                                                  u16* __restrict__ xb, float* __restrict__ xf) {
  int n = blockIdx.x;
  for (int c = threadIdx.x; c < D; c += 256) {
    float v = We[(size_t)(V - 1) * D + c] + be[c] + pos[c];
    size_t idx = (size_t)(n * TVAL) * D + c;
    xb[idx] = f2b(v);
    xf[idx] = v;
  }
}

// ---------------- main GEMM (BK=64) ----------------
// C[M,N] = A[M,K] @ Bt[N,K]^T ; A row stride lda. EPI: 0=embed(remap+pos)
// 1=bias->bf16 ; 2=bias+res(f32)->f32 ; 3=bias+gelu->bf16
template<int EPI>
__global__ __launch_bounds__(256) void gemm_bt(
    const u16* __restrict__ A, const u16* __restrict__ Bt,
    const float* __restrict__ bias, const float* __restrict__ resf,
    const float* __restrict__ pos, u16* __restrict__ Cb, float* __restrict__ Cf,
    int N, int K, int lda) {
  __shared__ __align__(16) u16 sA[8192];
  __shared__ __align__(16) u16 sB[8192];
  const int tid = threadIdx.x, wave = tid >> 6, lane = tid & 63;
  const int fr = lane & 15, fc8 = (lane >> 4) << 3;
  const int rA = blockIdx.y * 128, rB = blockIdx.x * 128;
  const u16* gA0 = A + (size_t)(rA + wave * 16 + fr) * lda + fc8;
  const u16* gA1 = A + (size_t)(rA + 64 + wave * 16 + fr) * lda + fc8;
  const u16* gB0 = Bt + (size_t)(rB + wave * 16 + fr) * K + fc8;
  const u16* gB1 = Bt + (size_t)(rB + 64 + wave * 16 + fr) * K + fc8;
  u16* lA0 = sA + wave * 512;
  u16* lA1 = sA + (4 + wave) * 512;
  u16* lB0 = sB + wave * 512;
  u16* lB1 = sB + (4 + wave) * 512;
  const int wm = wave & 1, wn = wave >> 1;
  f32x4 acc[4][4];
  #pragma unroll
  for (int mt = 0; mt < 4; ++mt)
    #pragma unroll
    for (int nt = 0; nt < 4; ++nt)
      #pragma unroll
      for (int r = 0; r < 4; ++r) acc[mt][nt][r] = 0.f;

  for (int kk = 0; kk < K; kk += 64) {
    __syncthreads();
    #pragma unroll
    for (int h = 0; h < 2; ++h) {
      async16(gA0 + kk + 32 * h, lA0 + 4096 * h);
      async16(gA1 + kk + 32 * h, lA1 + 4096 * h);
      async16(gB0 + kk + 32 * h, lB0 + 4096 * h);
      async16(gB1 + kk + 32 * h, lB1 + 4096 * h);
    }
    __syncthreads();
    #pragma unroll
    for (int h = 0; h < 2; ++h) {
      bfrag af[4], bfr[4];
      #pragma unroll
      for (int t = 0; t < 4; ++t)
        af[t] = *(const bfrag*)(sA + h * 4096 + (wm * 4 + t) * 512 + lane * 8);
      #pragma unroll
      for (int t = 0; t < 4; ++t)
        bfr[t] = *(const bfrag*)(sB + h * 4096 + (wn * 4 + t) * 512 + lane * 8);
      #pragma unroll
      for (int mt = 0; mt < 4; ++mt)
        #pragma unroll
        for (int nt = 0; nt < 4; ++nt)
          acc[mt][nt] = mfma16(af[mt], bfr[nt], acc[mt][nt]);
    }
  }

  const int r0 = rA + wm * 64;
  const int c0 = rB + wn * 64;
  #pragma unroll
  for (int mt = 0; mt < 4; ++mt) {
    #pragma unroll
    for (int nt = 0; nt < 4; ++nt) {
      int col = c0 + nt * 16 + fr;
      float bi = bias[col];
      f32x4 v = acc[mt][nt];
      #pragma unroll
      for (int r = 0; r < 4; ++r) {
        int row = r0 + mt * 16 + ((lane >> 4) << 2) + r;
        float val = v[r] + bi;
        if (EPI == 0) {
          int bidx = row >> 11;
          int s = row & 2047;
          size_t orow = (size_t)bidx * TVAL + s + 1;
          float tt = val + pos[(size_t)(s + 1) * D + col];
          Cb[orow * D + col] = f2b(tt);
          Cf[orow * D + col] = tt;
        } else if (EPI == 1) {
          Cb[(size_t)row * N + col] = f2b(val);
        } else if (EPI == 2) {
          Cf[(size_t)row * N + col] = val + resf[(size_t)row * N + col];
        } else {
          float gl = 0.5f * val * (1.f + erff(val * 0.70710678118f));
          Cb[(size_t)row * N + col] = f2b(gl);
        }
      }
    }
  }
}

// ---------------- rope + phi + K/V transpose (fused qkv buffer) ----------------
__global__ __launch_bounds__(256) void rope_kernel(
    u16* qkv, u16* __restrict__ Kt, u16* __restrict__ Vt,
    const float* __restrict__ ct, const float* __restrict__ snt) {
  const int stile = blockIdx.x, h = blockIdx.y, n = blockIdx.z;
  const int tid = threadIdx.x;
  const int sl = tid >> 2;
  const int g8 = (tid & 3) << 3;
  const int s = stile * 64 + sl;
  const bool valid = s < TVAL;
  const size_t row = (size_t)n * TVAL + s;
  float ql[8], qh[8], kl[8], kh[8];
  us8 vlo = {0,0,0,0,0,0,0,0}, vhi = {0,0,0,0,0,0,0,0};
  if (valid) {
    const u16* qp = qkv + row * QS + (size_t)h * DH;
    const u16* kp = qkv + row * QS + 1024 + (size_t)h * DH;
    const u16* vp = qkv + row * QS + 2048 + (size_t)h * DH;
    us8 a = *(const us8*)(qp + g8);
    us8 b = *(const us8*)(qp + 32 + g8);
    us8 c = *(const us8*)(kp + g8);
    us8 d = *(const us8*)(kp + 32 + g8);
    vlo = *(const us8*)(vp + g8);
    vhi = *(const us8*)(vp + 32 + g8);
    #pragma unroll
    for (int j = 0; j < 8; ++j) {
      ql[j] = b2f(a[j]); qh[j] = b2f(b[j]);
      kl[j] = b2f(c[j]); kh[j] = b2f(d[j]);
    }
  } else {
    #pragma unroll
    for (int j = 0; j < 8; ++j) { ql[j] = qh[j] = kl[j] = kh[j] = 0.f; }
  }
  const int se = valid ? s : 0;
  us8 qolo, qohi;
  u16 kolo[8], kohi[8];
  #pragma unroll
  for (int j = 0; j < 8; ++j) {
    float c = ct[se * 32 + g8 + j];
    float sn = snt[se * 32 + g8 + j];
    float x1 = ql[j] * c - qh[j] * sn;
    float x2 = qh[j] * c + ql[j] * sn;
    qolo[j] = f2b(phi_fn(x1));
    qohi[j] = f2b(phi_fn(x2));
    float y1 = kl[j] * c - kh[j] * sn;
    float y2 = kh[j] * c + kl[j] * sn;
    kolo[j] = f2b(phi_fn(y1));
    kohi[j] = f2b(phi_fn(y2));
  }
  if (valid) {
    u16* qp = qkv + row * QS + (size_t)h * DH;
    *(us8*)(qp + g8) = qolo;
    *(us8*)(qp + 32 + g8) = qohi;
  }
  __shared__ __align__(16) u16 tile[64][72];
  #pragma unroll
  for (int j = 0; j < 8; ++j) {
    tile[g8 + j][sl] = valid ? kolo[j] : (u16)0;
    tile[32 + g8 + j][sl] = valid ? kohi[j] : (u16)0;
  }
  __syncthreads();
  {
    const int dr = tid >> 2, ck = (tid & 3) << 4;
    const size_t ob = ((size_t)(n * H + h) * DH + dr) * TS + (size_t)stile * 64 + ck;
    us8 t0 = *(const us8*)&tile[dr][ck];
    us8 t1 = *(const us8*)&tile[dr][ck + 8];
    *(us8*)(Kt + ob) = t0;
    *(us8*)(Kt + ob + 8) = t1;
  }
  __syncthreads();
  #pragma unroll
  for (int j = 0; j < 8; ++j) {
    tile[g8 + j][sl] = valid ? vlo[j] : (u16)0;
    tile[32 + g8 + j][sl] = valid ? vhi[j] : (u16)0;
  }
  __syncthreads();
  {
    const int dr = tid >> 2, ck = (tid & 3) << 4;
    const size_t ob = ((size_t)(n * H + h) * DH + dr) * TS + (size_t)stile * 64 + ck;
    us8 t0 = *(const us8*)&tile[dr][ck];
    us8 t1 = *(const us8*)&tile[dr][ck + 8];
    *(us8*)(Vt + ob) = t0;
    *(us8*)(Vt + ob + 8) = t1;
  }
}

// ---------------- KV^T + Ksum per (n,h) ----------------
__global__ __launch_bounds__(256) void kv_kernel(
    const u16* __restrict__ Kt, const u16* __restrict__ Vt,
    u16* __restrict__ KVt, float* __restrict__ Ksum) {
  const int nh = blockIdx.x;
  const int tid = threadIdx.x, wave = tid >> 6, lane = tid & 63;
  const size_t base = (size_t)nh * DH * TS;
  const int fr = lane & 15, fc = (lane >> 4) << 3;
  f32x4 acc[4][4];
  #pragma unroll
  for (int a = 0; a < 4; ++a)
    #pragma unroll
    for (int b = 0; b < 4; ++b)
      #pragma unroll
      for (int r = 0; r < 4; ++r) acc[a][b][r] = 0.f;
  for (int c = wave; c < TS / 32; c += 4) {
    const int s0 = c * 32 + fc;
    bfrag av[4], bk[4];
    #pragma unroll
    for (int t = 0; t < 4; ++t) {
      av[t] = *(const bfrag*)(Vt + base + (size_t)(t * 16 + fr) * TS + s0);
      bk[t] = *(const bfrag*)(Kt + base + (size_t)(t * 16 + fr) * TS + s0);
    }
    #pragma unroll
    for (int mt = 0; mt < 4; ++mt)
      #pragma unroll
      for (int dt = 0; dt < 4; ++dt)
        acc[mt][dt] = mfma16(av[mt], bk[dt], acc[mt][dt]);
  }
  __shared__ float red[4096];
  for (int i = tid; i < 4096; i += 256) red[i] = 0.f;
  __syncthreads();
  #pragma unroll
  for (int mt = 0; mt < 4; ++mt)
    #pragma unroll
    for (int dt = 0; dt < 4; ++dt)
      #pragma unroll
      for (int r = 0; r < 4; ++r) {
        int m = mt * 16 + ((lane >> 4) << 2) + r;
        int dd = dt * 16 + fr;
        atomicAdd(&red[m * 64 + dd], acc[mt][dt][r]);
      }
  __syncthreads();
  for (int i = tid; i < 4096; i += 256) KVt[(size_t)nh * 4096 + i] = f2b(red[i]);
  float ks = 0.f;
  const int dd = tid & 63, part = tid >> 6;
  for (int s = part * (TS / 4); s < (part + 1) * (TS / 4); s += 8) {
    us8 t = *(const us8*)(Kt + base + (size_t)dd * TS + s);
    #pragma unroll
    for (int j = 0; j < 8; ++j) ks += b2f(t[j]);
  }
  __shared__ float ksr[64];
  if (tid < 64) ksr[tid] = 0.f;
  __syncthreads();
  atomicAdd(&ksr[dd], ks);
  __syncthreads();
  if (tid < 64) Ksum[nh * 64 + tid] = ksr[tid];
}

// ---------------- Z = 1/(Qf . Ksum + eps) ----------------
__global__ __launch_bounds__(256) void z_kernel(const u16* __restrict__ qkv,
                                                const float* __restrict__ Ksum,
                                                float* __restrict__ Z) {
  const int tid = threadIdx.x;
  const int row = blockIdx.x * 16 + (tid >> 4);
  const int h = tid & 15;
  if (row >= MVAL) return;
  const int n = row / TVAL;
  const u16* qp = qkv + (size_t)row * QS + h * DH;
  const float* kp = Ksum + (size_t)(n * 16 + h) * 64;
  float acc = 0.f;
  #pragma unroll
  for (int j = 0; j < 64; j += 8) {
    us8 t = *(const us8*)(qp + j);
    #pragma unroll
    for (int j2 = 0; j2 < 8; ++j2) acc += b2f(t[j2]) * kp[j + j2];
  }
  Z[(size_t)row * 16 + h] = 1.f / (acc + 1e-6f);
}

// ---------------- attn = (Qf @ KVt^T) * Z -> v-section of qkv ----------------
__global__ __launch_bounds__(256) void attn_kernel(
    u16* qkv, const u16* __restrict__ KVt,
    const float* __restrict__ Z) {
  const int mt5 = blockIdx.x, nh = blockIdx.y, n = nh >> 4, h = nh & 15;
  const int tid = threadIdx.x, wave = tid >> 6, lane = tid & 63;
  const int fr = lane & 15, fc = (lane >> 4) << 3;
  f32x4 acc[2][4];
  #pragma unroll
  for (int a = 0; a < 2; ++a)
    #pragma unroll
    for (int b = 0; b < 4; ++b)
      #pragma unroll
      for (int r = 0; r < 4; ++r) acc[a][b][r] = 0.f;
  #pragma unroll
  for (int kc = 0; kc < 2; ++kc) {
    bfrag aq[2], bkv[4];
    #pragma unroll
    for (int m2 = 0; m2 < 2; ++m2) {
      int sr = mt5 * 128 + wave * 32 + m2 * 16 + fr;
      if (sr > 2048) sr = 2048;
      aq[m2] = *(const bfrag*)(qkv + ((size_t)n * TVAL + sr) * QS + h * DH + kc * 32 + fc);
    }
    #pragma unroll
    for (int nt = 0; nt < 4; ++nt)
      bkv[nt] = *(const bfrag*)(KVt + (size_t)nh * 4096 + (nt * 16 + fr) * 64 + kc * 32 + fc);
    #pragma unroll
    for (int m2 = 0; m2 < 2; ++m2)
      #pragma unroll
      for (int nt = 0; nt < 4; ++nt)
        acc[m2][nt] = mfma16(aq[m2], bkv[nt], acc[m2][nt]);
  }
  #pragma unroll
  for (int m2 = 0; m2 < 2; ++m2)
    #pragma unroll
    for (int nt = 0; nt < 4; ++nt)
      #pragma unroll
      for (int r = 0; r < 4; ++r) {
        int s = mt5 * 128 + wave * 32 + m2 * 16 + ((lane >> 4) << 2) + r;
        if (s < TVAL) {
          size_t row = (size_t)n * TVAL + s;
          float z = Z[row * 16 + h];
          qkv[row * QS + 2048 + h * DH + nt * 16 + fr] = f2b(acc[m2][nt][r] * z);
        }
      }
}

// ---------------- LayerNorm (f32 in -> bf16 out stride ostride [, f32 out]) ----------------
template<bool WF>
__global__ __launch_bounds__(256) void ln_kernel(const float* in, const float* __restrict__ g,
                                                 const float* __restrict__ b,
                                                 u16* __restrict__ ob, int ostride, float* of) {
  const int tid = threadIdx.x, wave = tid >> 6, lane = tid & 63;
  const size_t row = (size_t)blockIdx.x * 4 + wave;
  const float* rp = in + row * D + lane * 16;
  float v[16];
  #pragma unroll
  for (int i = 0; i < 16; i += 4) {
    fvec4 t = *(const fvec4*)(rp + i);
    v[i] = t[0]; v[i + 1] = t[1]; v[i + 2] = t[2]; v[i + 3] = t[3];
  }
  float s = 0.f, s2 = 0.f;
  #pragma unroll
  for (int i = 0; i < 16; ++i) { s += v[i]; s2 += v[i] * v[i]; }
  #pragma unroll
  for (int m = 1; m < 64; m <<= 1) { s += __shfl_xor(s, m); s2 += __shfl_xor(s2, m); }
  float mean = s * (1.f / 1024.f);
  float var = s2 * (1.f / 1024.f) - mean * mean;
  float rstd = rsqrtf(var + 1e-5f);
  const int c0 = lane * 16;
  us8 o0, o1;
  #pragma unroll
  for (int i = 0; i < 16; ++i) {
    float o = (v[i] - mean) * rstd * g[c0 + i] + b[c0 + i];
    if (i < 8) o0[i] = f2b(o); else o1[i - 8] = f2b(o);
    if (WF) of[row * D + c0 + i] = o;
  }
  *(us8*)(ob + row * (size_t)ostride + c0) = o0;
  *(us8*)(ob + row * (size_t)ostride + c0 + 8) = o1;
}

// ---------------- final LN on CLS rows ----------------
__global__ __launch_bounds__(256) void lnf_kernel(const float* __restrict__ xf,
                                                  const float* __restrict__ gN,
                                                  const float* __restrict__ bN,
                                                  float* __restrict__ lnf) {
  const int n = blockIdx.x, tid = threadIdx.x;
  const float* rp = xf + (size_t)n * TVAL * D;
  float v[4];
  #pragma unroll
  for (int i = 0; i < 4; ++i) v[i] = rp[tid * 4 + i];
  float s = v[0] + v[1] + v[2] + v[3];
  float s2 = v[0]*v[0] + v[1]*v[1] + v[2]*v[2] + v[3]*v[3];
  #pragma unroll
  for (int m = 1; m < 64; m <<= 1) { s += __shfl_xor(s, m); s2 += __shfl_xor(s2, m); }
  __shared__ float rs[4], rs2[4];
  const int wave = tid >> 6, lane = tid & 63;
  if (lane == 0) { rs[wave] = s; rs2[wave] = s2; }
  __syncthreads();
  s = rs[0] + rs[1] + rs[2] + rs[3];
  s2 = rs2[0] + rs2[1] + rs2[2] + rs2[3];
  float mean = s * (1.f / 1024.f);
  float var = s2 * (1.f / 1024.f) - mean * mean;
  float rstd = rsqrtf(var + 1e-5f);
  #pragma unroll
  for (int i = 0; i < 4; ++i) {
    int c = tid * 4 + i;
    lnf[n * D + c] = (v[i] - mean) * rstd * gN[c] + bN[c];
  }
}

// ---------------- out = lnf @ Wout + bout ----------------
__global__ __launch_bounds__(256) void out_kernel(const float* __restrict__ lnf,
                                                  const float* __restrict__ Wout,
                                                  const float* __restrict__ bout,
                                                  float* __restrict__ out) {
  __shared__ float xs[8 * 1024];
  for (int i = threadIdx.x; i < 8192; i += 256) xs[i] = lnf[i];
  __syncthreads();
  const int j = blockIdx.x * 256 + threadIdx.x;
  float acc[8];
  float bj = bout[j];
  #pragma unroll
  for (int n = 0; n < 8; ++n) acc[n] = bj;
  for (int k = 0; k < 1024; ++k) {
    float w = Wout[(size_t)k * 4096 + j];
    #pragma unroll
    for (int n = 0; n < 8; ++n) acc[n] += xs[n * 1024 + k] * w;
  }
  #pragma unroll
  for (int n = 0; n < 8; ++n) out[(size_t)n * 4096 + j] = acc[n];
}

// ---------------- host ----------------
extern "C" void kernel_launch(void* const* d_in, const int* in_sizes, int n_in,
                              void* d_out, int out_size, void* d_ws, size_t ws_size,
                              hipStream_t stream) {
  const float* inputs = (const float*)d_in[0];
  const float* We   = (const float*)d_in[1];
  const float* be   = (const float*)d_in[2];
  const float* pos  = (const float*)d_in[3];
  const float* Wq   = (const float*)d_in[4];
  const float* bq   = (const float*)d_in[5];
  const float* Wk   = (const float*)d_in[6];
  const float* bk   = (const float*)d_in[7];
  const float* Wv   = (const float*)d_in[8];
  const float* bv   = (const float*)d_in[9];
  const float* Wo   = (const float*)d_in[10];
  const float* bo   = (const float*)d_in[11];
  const float* ln1g = (const float*)d_in[12];
  const float* ln1b = (const float*)d_in[13];
  const float* W1   = (const float*)d_in[14];
  const float* b1   = (const float*)d_in[15];
  const float* W2   = (const float*)d_in[16];
  const float* b2   = (const float*)d_in[17];
  const float* ln2g = (const float*)d_in[18];
  const float* ln2b = (const float*)d_in[19];
  const float* gN   = (const float*)d_in[20];
  const float* bN   = (const float*)d_in[21];
  const float* Wout = (const float*)d_in[22];
  const float* bout = (const float*)d_in[23];
  float* out = (float*)d_out;

  char* p = (char*)d_ws;
  auto alloc = [&](size_t b) { char* r = p; p += (b + 255) & ~(size_t)255; return r; };
  u16*   xb   = (u16*)alloc((size_t)MPAD * D * 2);
  float* xf   = (float*)alloc((size_t)MPAD * D * 4);
  float* hf   = (float*)alloc((size_t)MPAD * D * 4);
  u16*   qkvb = (u16*)alloc((size_t)MPAD * QS * 2);
  u16*   Kt   = (u16*)alloc((size_t)128 * DH * TS * 2);
  u16*   Vt   = (u16*)alloc((size_t)128 * DH * TS * 2);
  u16*   ffb  = (u16*)alloc((size_t)MPAD * FF * 2);
  u16*   inb  = ffb;  // alias: inputs_bf16 used only before ffn
  u16*   WeT  = (u16*)alloc((size_t)V * D * 2);
  u16*   WqkvT= (u16*)alloc((size_t)QS * D * 2);
  u16*   WoT  = (u16*)alloc((size_t)D * D * 2);
  u16*   W1T  = (u16*)alloc((size_t)D * FF * 2);
  u16*   W2T  = (u16*)alloc((size_t)FF * D * 2);
  u16*   KVt  = (u16*)alloc((size_t)128 * 64 * 64 * 2);
  float* Ksum = (float*)alloc((size_t)128 * 64 * 4);
  float* Zb   = (float*)alloc((size_t)MPAD * 16 * 4);
  float* ct   = (float*)alloc((size_t)TVAL * 32 * 4);
  float* snt  = (float*)alloc((size_t)TVAL * 32 * 4);
  float* lnf  = (float*)alloc((size_t)8 * D * 4);
  float* bqkv = (float*)alloc((size_t)NL * QS * 4);

  hipMemsetAsync(Kt, 0, (size_t)128 * DH * TS * 2, stream);
  hipMemsetAsync(Vt, 0, (size_t)128 * DH * TS * 2, stream);
  rope_table<<<(TVAL * 32 + 255) / 256, 256, 0, stream>>>(ct, snt);
  pack_bias<<<(NL * QS + 255) / 256, 256, 0, stream>>>(bq, bk, bv, bqkv);
  conv_kernel<<<65536, 256, 0, stream>>>(inputs, inb, (long)NB * SEQ * V);
  transposeW<<<dim3(V / 64, D / 64, 1), 256, 0, stream>>>(We, WeT, V, D);
  cls_kernel<<<8, 256, 0, stream>>>(We, be, pos, xb, xf);
  gemm_bt<0><<<dim3(D / 128, 16384 / 128), 256, 0, stream>>>(
      inb, WeT, be, nullptr, pos, xb, xf, D, V, V);

  for (int l = 0; l < NL; ++l) {
    transposeW<<<dim3(16, 16, 1), 256, 0, stream>>>(Wq + (size_t)l * D * D, WqkvT, D, D);
    transposeW<<<dim3(16, 16, 1), 256, 0, stream>>>(Wk + (size_t)l * D * D, WqkvT + (size_t)1024 * D, D, D);
    transposeW<<<dim3(16, 16, 1), 256, 0, stream>>>(Wv + (size_t)l * D * D, WqkvT + (size_t)2048 * D, D, D);
    transposeW<<<dim3(16, 16, 1), 256, 0, stream>>>(Wo + (size_t)l * D * D, WoT, D, D);
    transposeW<<<dim3(16, 64, 1), 256, 0, stream>>>(W1 + (size_t)l * D * FF, W1T, D, FF);
    transposeW<<<dim3(64, 16, 1), 256, 0, stream>>>(W2 + (size_t)l * FF * D, W2T, FF, D);

    // fused QKV: [MPAD,3072]
    gemm_bt<1><<<dim3(24, 129), 256, 0, stream>>>(xb, WqkvT, bqkv + l * QS, nullptr, nullptr,
                                                  qkvb, nullptr, QS, D, D);
    rope_kernel<<<dim3(33, 16, 8), 256, 0, stream>>>(qkvb, Kt, Vt, ct, snt);
    kv_kernel<<<128, 256, 0, stream>>>(Kt, Vt, KVt, Ksum);
    z_kernel<<<(MVAL + 15) / 16, 256, 0, stream>>>(qkvb, Ksum, Zb);
    attn_kernel<<<dim3(17, 128), 256, 0, stream>>>(qkvb, KVt, Zb);
    // hf = x + attn@Wo + bo   (attn lives in v-section, lda=QS)
    gemm_bt<2><<<dim3(8, 129), 256, 0, stream>>>(qkvb + 2048, WoT, bo + l * D, xf, nullptr,
                                                 nullptr, hf, D, D, QS);
    // x1 = LN1(hf): q-section = bf16(x1), xf = fp32 x1
    ln_kernel<true><<<MPAD / 4, 256, 0, stream>>>(hf, ln1g + l * D, ln1b + l * D, qkvb, QS, xf);
    gemm_bt<3><<<dim3(32, 129), 256, 0, stream>>>(qkvb, W1T, b1 + l * FF, nullptr, nullptr,
                                                  ffb, nullptr, FF, D, QS);
    // hf = x1 + ff@W2 + b2
    gemm_bt<2><<<dim3(8, 129), 256, 0, stream>>>(ffb, W2T, b2 + l * D, xf, nullptr,
                                                 nullptr, hf, D, FF, FF);
    // x2 = LN2(hf)
    ln_kernel<true><<<MPAD / 4, 256, 0, stream>>>(hf, ln2g + l * D, ln2b + l * D, xb, D, xf);
  }

  lnf_kernel<<<8, 256, 0, stream>>>(xf, gN, bN, lnf);
  out_kernel<<<16, 256, 0, stream>>>(lnf, Wout, bout, out);
}